// Round 4
// baseline (167.288 us; speedup 1.0000x reference)
//
#include <hip/hip_runtime.h>

// Problem constants (from reference setup_inputs)
#define NB 8
#define LQ 512
#define LC 2048
#define DD 768

typedef _Float16 f16x8 __attribute__((ext_vector_type(8)));
typedef _Float16 f16x4 __attribute__((ext_vector_type(4)));
typedef float    f32x4 __attribute__((ext_vector_type(4)));

// ---------------------------------------------------------------------------
// K0: convert Q fp32 -> Qh [b][q][d] fp16  AND  QhT [b][d][q] fp16
// ---------------------------------------------------------------------------
__global__ __launch_bounds__(256) void preconvert_q(const float* __restrict__ Q,
                                                    _Float16* __restrict__ Qh,
                                                    _Float16* __restrict__ QhT) {
    __shared__ _Float16 lt[64][68];
    const int blk = blockIdx.x;
    const int b   = blk / 96;
    const int rem = blk % 96;
    const int q0  = (rem / 12) * 64;
    const int d0  = (rem % 12) * 64;
    const int t   = threadIdx.x;
    const int tr  = t >> 4;
    const int tc  = t & 15;

    const float* Qb  = Q  + ((size_t)b * LQ + q0) * DD + d0;
    _Float16*    Qhb = Qh + ((size_t)b * LQ + q0) * DD + d0;

#pragma unroll
    for (int i = 0; i < 4; i++) {
        const int row = i * 16 + tr;
        const int col = tc * 4;
        f32x4 v = *(const f32x4*)(Qb + (size_t)row * DD + col);
        f16x4 h;
        h.x = (_Float16)v.x; h.y = (_Float16)v.y;
        h.z = (_Float16)v.z; h.w = (_Float16)v.w;
        *(f16x4*)(Qhb + (size_t)row * DD + col) = h;
        *(f16x4*)&lt[row][col] = h;
    }
    __syncthreads();

    _Float16* QTb = QhT + ((size_t)b * DD + d0) * LQ + q0;
#pragma unroll
    for (int i = 0; i < 4; i++) {
        const int drow = i * 16 + tr;
        const int qc   = tc * 4;
        f16x4 h;
        h.x = lt[qc + 0][drow];
        h.y = lt[qc + 1][drow];
        h.z = lt[qc + 2][drow];
        h.w = lt[qc + 3][drow];
        *(f16x4*)(QTb + (size_t)drow * LQ + qc) = h;
    }
}

// ---------------------------------------------------------------------------
// Main fused kernel v10: 1024-thread blocks -> 4 waves/SIMD latency hiding.
//
// R3 post-mortem: explicit register rings were NEUTRAL (VGPR stuck at 124 —
// the scheduler re-sank the prefetches; source-level ILP can't be forced).
// Structural issue: 160KB LDS -> one 8-wave block/CU -> 2 waves/SIMD. Per
// SIMD round = 2 x 78cy MFMA = 156cy vs ~300cy L2 latency -> matrix pipe
// starves regardless of schedule.
//
// v10: same 256 blocks / same 160KB LDS map / same CM=64 tiling, but 16
// waves per block (1024 threads) -> 4 waves/SIMD. Per-wave width halves
// (phase A: 32 q-cols, nt=2; phase C: 48 d-cols, nt=3), halving acc
// pressure so the 128-VGPR cap of __launch_bounds__(1024,4) fits. Latency
// is hidden by 2x more independent per-SIMD load streams (TLP, not ILP).
//
// LDS (160KB): A [64][768] f16 swizzled [0,98304) — alive through epilogue
// (gate from LDS; ctx read once). P [64][512] f16 swizzled [98304,163840).
// red_max/red_sum [16][64] f32 alias the first 8KB of P (X3 WAR barrier).
// K-loops barrier-free; B-frags direct from L2-resident Qh/QhT.
// ---------------------------------------------------------------------------
#define CM        64
#define A_SLOTS   96          // 16B slots per A row (768 f16)
#define P_OFF     98304
#define P_SLOTS   64          // 16B slots per P row (512 f16)
#define SMEM_BYTES 163840

__global__ __launch_bounds__(1024, 4) void gated_attn(const float* __restrict__ ctx,
                                                      const _Float16* __restrict__ Qh,
                                                      const _Float16* __restrict__ QhT,
                                                      float* __restrict__ out) {
    __shared__ __align__(16) char smem[SMEM_BYTES];
    float (*red_max)[64] = (float (*)[64])(smem + P_OFF);
    float (*red_sum)[64] = (float (*)[64])(smem + P_OFF + 4096);

    const int b    = blockIdx.x & 7;          // XCD-affine batch
    const int c0   = (blockIdx.x >> 3) * CM;
    const int t    = threadIdx.x;
    const int w    = t >> 6;                  // wave 0..15
    const int lane = t & 63;
    const int quad = lane >> 4;
    const int l15  = lane & 15;

    const float*    Cb  = ctx + ((size_t)b * LC + c0) * DD;
    const _Float16* Qhb = Qh  + (size_t)b * LQ * DD;
    const _Float16* QTb = QhT + (size_t)b * DD * LQ;

    // phase A: wave w owns q-cols [w*32, w*32+32); phase C: d-cols [w*48, w*48+48)
    const _Float16* bqb = Qhb + (size_t)(w * 32 + l15) * DD + quad * 8;
    const _Float16* cqb = QTb + (size_t)(w * 48 + l15) * LQ + quad * 8;

    // -------- Phase-A B-frag preload (kc=0,1): drained free by the barrier --
    f16x8 bP[3][2];
#pragma unroll
    for (int s = 0; s < 2; s++)
#pragma unroll
        for (int nt = 0; nt < 2; nt++)
            bP[s][nt] = *(const f16x8*)(bqb + (size_t)(nt * 16) * DD + s * 32);

    // ---------------- Stage A-tile (ctx f32 -> f16, swizzled) ----------------
#pragma unroll
    for (int i = 0; i < 6; i++) {
        const int idx = i * 1024 + t;
        const int row = idx / 96;
        const int c16 = idx % 96;
        const float* p = Cb + (size_t)row * DD + c16 * 8;
        f32x4 f0 = *(const f32x4*)p;
        f32x4 f1 = *(const f32x4*)(p + 4);
        f16x8 v;
        v[0] = (_Float16)f0.x; v[1] = (_Float16)f0.y;
        v[2] = (_Float16)f0.z; v[3] = (_Float16)f0.w;
        v[4] = (_Float16)f1.x; v[5] = (_Float16)f1.y;
        v[6] = (_Float16)f1.z; v[7] = (_Float16)f1.w;
        const int s16 = row * A_SLOTS + ((c16 & ~7) | ((c16 ^ row) & 7));
        *(f16x8*)(smem + (size_t)s16 * 16) = v;
    }
    __syncthreads();   // publish ldsA (drains bP[0..1] loads too)

    // ---------------- Phase A: S = A @ Qh^T (no barriers) ----------------
    f32x4 acc[4][2];
#pragma unroll
    for (int mt = 0; mt < 4; mt++)
#pragma unroll
        for (int nt = 0; nt < 2; nt++)
            acc[mt][nt] = (f32x4){0.f, 0.f, 0.f, 0.f};

    f16x8 aP[2][4];
    {
        const int sw0 = (quad & ~7) | ((quad ^ l15) & 7);   // kc=0, c16=quad
#pragma unroll
        for (int mt = 0; mt < 4; mt++)
            aP[0][mt] = *(const f16x8*)(smem + (size_t)((mt * 16 + l15) * A_SLOTS + sw0) * 16);
    }

#pragma unroll
    for (int kc = 0; kc < 24; kc++) {
        if (kc + 2 < 24) {
#pragma unroll
            for (int nt = 0; nt < 2; nt++)
                bP[(kc + 2) % 3][nt] = *(const f16x8*)(bqb + (size_t)(nt * 16) * DD + (kc + 2) * 32);
        }
        if (kc + 1 < 24) {
            const int c16 = (kc + 1) * 4 + quad;
            const int sw  = (c16 & ~7) | ((c16 ^ l15) & 7);
#pragma unroll
            for (int mt = 0; mt < 4; mt++)
                aP[(kc + 1) & 1][mt] = *(const f16x8*)(smem + (size_t)((mt * 16 + l15) * A_SLOTS + sw) * 16);
        }
        __builtin_amdgcn_s_setprio(1);
#pragma unroll
        for (int nt = 0; nt < 2; nt++)
#pragma unroll
            for (int mt = 0; mt < 4; mt++)
                acc[mt][nt] = __builtin_amdgcn_mfma_f32_16x16x32_f16(aP[kc & 1][mt], bP[kc % 3][nt], acc[mt][nt], 0, 0, 0);
        __builtin_amdgcn_s_setprio(0);
    }

    // -------- Phase-C B-frag preload (kc=0,1): latency hides under softmax --
    f16x8 cP[3][3];
#pragma unroll
    for (int s = 0; s < 2; s++)
#pragma unroll
        for (int nt = 0; nt < 3; nt++)
            cP[s][nt] = *(const f16x8*)(cqb + (size_t)(nt * 16) * LQ + s * 32);

    // ---------------- Softmax over q ----------------
    float rm[4][4];
#pragma unroll
    for (int mt = 0; mt < 4; mt++)
#pragma unroll
        for (int r = 0; r < 4; r++)
            rm[mt][r] = -1e30f;
#pragma unroll
    for (int mt = 0; mt < 4; mt++)
#pragma unroll
        for (int nt = 0; nt < 2; nt++) {
            rm[mt][0] = fmaxf(rm[mt][0], acc[mt][nt].x);
            rm[mt][1] = fmaxf(rm[mt][1], acc[mt][nt].y);
            rm[mt][2] = fmaxf(rm[mt][2], acc[mt][nt].z);
            rm[mt][3] = fmaxf(rm[mt][3], acc[mt][nt].w);
        }
#pragma unroll
    for (int off = 1; off < 16; off <<= 1)
#pragma unroll
        for (int mt = 0; mt < 4; mt++)
#pragma unroll
            for (int r = 0; r < 4; r++)
                rm[mt][r] = fmaxf(rm[mt][r], __shfl_xor(rm[mt][r], off));
    if (l15 == 0) {
#pragma unroll
        for (int mt = 0; mt < 4; mt++)
#pragma unroll
            for (int r = 0; r < 4; r++)
                red_max[w][mt * 16 + quad * 4 + r] = rm[mt][r];
    }
    __syncthreads();   // [X1] publish red_max (all phase-A LDS reads drained)

    float fm[4][4];
#pragma unroll
    for (int mt = 0; mt < 4; mt++)
#pragma unroll
        for (int r = 0; r < 4; r++) {
            const int row = mt * 16 + quad * 4 + r;
            float m = red_max[0][row];
#pragma unroll
            for (int j = 1; j < 16; j++) m = fmaxf(m, red_max[j][row]);
            fm[mt][r] = m;
        }
    float rs[4][4];
#pragma unroll
    for (int mt = 0; mt < 4; mt++)
#pragma unroll
        for (int r = 0; r < 4; r++)
            rs[mt][r] = 0.f;
#pragma unroll
    for (int mt = 0; mt < 4; mt++)
#pragma unroll
        for (int nt = 0; nt < 2; nt++) {
            float e0 = __expf(acc[mt][nt].x - fm[mt][0]);
            float e1 = __expf(acc[mt][nt].y - fm[mt][1]);
            float e2 = __expf(acc[mt][nt].z - fm[mt][2]);
            float e3 = __expf(acc[mt][nt].w - fm[mt][3]);
            acc[mt][nt].x = e0; acc[mt][nt].y = e1;
            acc[mt][nt].z = e2; acc[mt][nt].w = e3;
            rs[mt][0] += e0; rs[mt][1] += e1; rs[mt][2] += e2; rs[mt][3] += e3;
        }
#pragma unroll
    for (int off = 1; off < 16; off <<= 1)
#pragma unroll
        for (int mt = 0; mt < 4; mt++)
#pragma unroll
            for (int r = 0; r < 4; r++)
                rs[mt][r] += __shfl_xor(rs[mt][r], off);
    if (l15 == 0) {
#pragma unroll
        for (int mt = 0; mt < 4; mt++)
#pragma unroll
            for (int r = 0; r < 4; r++)
                red_sum[w][mt * 16 + quad * 4 + r] = rs[mt][r];
    }
    __syncthreads();   // [X2] publish red_sum

#pragma unroll
    for (int mt = 0; mt < 4; mt++)
#pragma unroll
        for (int r = 0; r < 4; r++) {
            const int row = mt * 16 + quad * 4 + r;
            float s = 0.f;
#pragma unroll
            for (int j = 0; j < 16; j++) s += red_sum[j][row];
            const float inv = 1.0f / s;
#pragma unroll
            for (int nt = 0; nt < 2; nt++) {
                acc[mt][nt].x = (r == 0) ? acc[mt][nt].x * inv : acc[mt][nt].x;
                acc[mt][nt].y = (r == 1) ? acc[mt][nt].y * inv : acc[mt][nt].y;
                acc[mt][nt].z = (r == 2) ? acc[mt][nt].z * inv : acc[mt][nt].z;
                acc[mt][nt].w = (r == 3) ? acc[mt][nt].w * inv : acc[mt][nt].w;
            }
        }
    __syncthreads();   // [X3] red region reads drained; P writes may overwrite it

    // write P (f16, swizzled)
#pragma unroll
    for (int mt = 0; mt < 4; mt++)
#pragma unroll
        for (int r = 0; r < 4; r++) {
            const int row = mt * 16 + quad * 4 + r;
#pragma unroll
            for (int nt = 0; nt < 2; nt++) {
                const int q = w * 32 + nt * 16 + l15;
                float v = (r == 0 ? acc[mt][nt].x : r == 1 ? acc[mt][nt].y
                          : r == 2 ? acc[mt][nt].z : acc[mt][nt].w);
                const int c16 = q >> 3;
                const int s16 = row * P_SLOTS + ((c16 & ~7) | ((c16 ^ row) & 7));
                *(_Float16*)(smem + P_OFF + (size_t)s16 * 16 + (q & 7) * 2) = (_Float16)v;
            }
        }
    __syncthreads();   // [X4] publish P

    // ---------------- Phase C: awq = P @ Q (no barriers) ----------------
    f32x4 acc2[4][3];
#pragma unroll
    for (int mt = 0; mt < 4; mt++)
#pragma unroll
        for (int nt = 0; nt < 3; nt++)
            acc2[mt][nt] = (f32x4){0.f, 0.f, 0.f, 0.f};

    f16x8 pP[2][4];
    {
        const int sw0 = (quad & ~7) | ((quad ^ l15) & 7);   // kc=0, c16=quad
#pragma unroll
        for (int mt = 0; mt < 4; mt++)
            pP[0][mt] = *(const f16x8*)(smem + P_OFF + (size_t)((mt * 16 + l15) * P_SLOTS + sw0) * 16);
    }

#pragma unroll
    for (int kc = 0; kc < 16; kc++) {
        if (kc + 2 < 16) {
#pragma unroll
            for (int nt = 0; nt < 3; nt++)
                cP[(kc + 2) % 3][nt] = *(const f16x8*)(cqb + (size_t)(nt * 16) * LQ + (kc + 2) * 32);
        }
        if (kc + 1 < 16) {
            const int c16 = (kc + 1) * 4 + quad;
            const int sw  = (c16 & ~7) | ((c16 ^ l15) & 7);
#pragma unroll
            for (int mt = 0; mt < 4; mt++)
                pP[(kc + 1) & 1][mt] = *(const f16x8*)(smem + P_OFF + (size_t)((mt * 16 + l15) * P_SLOTS + sw) * 16);
        }
        __builtin_amdgcn_s_setprio(1);
#pragma unroll
        for (int nt = 0; nt < 3; nt++)
#pragma unroll
            for (int mt = 0; mt < 4; mt++)
                acc2[mt][nt] = __builtin_amdgcn_mfma_f32_16x16x32_f16(pP[kc & 1][mt], cP[kc % 3][nt], acc2[mt][nt], 0, 0, 0);
        __builtin_amdgcn_s_setprio(0);
    }

    // ---------------- Epilogue: out = gate(LDS A-tile) * awq ----------------
#pragma unroll
    for (int mt = 0; mt < 4; mt++)
#pragma unroll
        for (int nt = 0; nt < 3; nt++) {
            const int col = w * 48 + nt * 16 + l15;
            const int c16 = col >> 3;
            const int sub = col & 7;
#pragma unroll
            for (int r = 0; r < 4; r++) {
                const int rl  = mt * 16 + quad * 4 + r;
                const int s16 = rl * A_SLOTS + ((c16 & ~7) | ((c16 ^ rl) & 7));
                const float g = (float)*(const _Float16*)(smem + (size_t)s16 * 16 + sub * 2);
                float v = (r == 0 ? acc2[mt][nt].x : r == 1 ? acc2[mt][nt].y
                          : r == 2 ? acc2[mt][nt].z : acc2[mt][nt].w);
                out[((size_t)b * LC + c0 + rl) * DD + col] = g * v;
            }
        }
}

extern "C" void kernel_launch(void* const* d_in, const int* in_sizes, int n_in,
                              void* d_out, int out_size, void* d_ws, size_t ws_size,
                              hipStream_t stream) {
    const float* ctx = (const float*)d_in[0];   // [8][2048][768] f32
    const float* q   = (const float*)d_in[1];   // [8][512][768]  f32
    float* out = (float*)d_out;

    const size_t nQ = (size_t)NB * LQ * DD;     // 3,145,728
    _Float16* Qh  = (_Float16*)d_ws;
    _Float16* QhT = Qh + nQ;

    preconvert_q<<<dim3(NB * 96), dim3(256), 0, stream>>>(q, Qh, QhT);
    gated_attn<<<dim3(NB * (LC / CM)), dim3(1024), 0, stream>>>(ctx, Qh, QhT, out);
}

// Round 5
// 152.301 us; speedup vs baseline: 1.0984x; 1.0984x over previous
//
#include <hip/hip_runtime.h>

// Problem constants (from reference setup_inputs)
#define NB 8
#define LQ 512
#define LC 2048
#define DD 768

typedef _Float16 f16x8 __attribute__((ext_vector_type(8)));
typedef _Float16 f16x4 __attribute__((ext_vector_type(4)));
typedef float    f32x4 __attribute__((ext_vector_type(4)));

// ---------------------------------------------------------------------------
// K0: convert Q fp32 -> Qh [b][q][d] fp16  AND  QhT [b][d][q] fp16
// ---------------------------------------------------------------------------
__global__ __launch_bounds__(256) void preconvert_q(const float* __restrict__ Q,
                                                    _Float16* __restrict__ Qh,
                                                    _Float16* __restrict__ QhT) {
    __shared__ _Float16 lt[64][68];
    const int blk = blockIdx.x;
    const int b   = blk / 96;
    const int rem = blk % 96;
    const int q0  = (rem / 12) * 64;
    const int d0  = (rem % 12) * 64;
    const int t   = threadIdx.x;
    const int tr  = t >> 4;
    const int tc  = t & 15;

    const float* Qb  = Q  + ((size_t)b * LQ + q0) * DD + d0;
    _Float16*    Qhb = Qh + ((size_t)b * LQ + q0) * DD + d0;

#pragma unroll
    for (int i = 0; i < 4; i++) {
        const int row = i * 16 + tr;
        const int col = tc * 4;
        f32x4 v = *(const f32x4*)(Qb + (size_t)row * DD + col);
        f16x4 h;
        h.x = (_Float16)v.x; h.y = (_Float16)v.y;
        h.z = (_Float16)v.z; h.w = (_Float16)v.w;
        *(f16x4*)(Qhb + (size_t)row * DD + col) = h;
        *(f16x4*)&lt[row][col] = h;
    }
    __syncthreads();

    _Float16* QTb = QhT + ((size_t)b * DD + d0) * LQ + q0;
#pragma unroll
    for (int i = 0; i < 4; i++) {
        const int drow = i * 16 + tr;
        const int qc   = tc * 4;
        f16x4 h;
        h.x = lt[qc + 0][drow];
        h.y = lt[qc + 1][drow];
        h.z = lt[qc + 2][drow];
        h.w = lt[qc + 3][drow];
        *(f16x4*)(QTb + (size_t)drow * LQ + qc) = h;
    }
}

// ---------------------------------------------------------------------------
// Main fused kernel v11: v9 structure + UNTRACKED asm loads with hand-counted
// vmcnt in the K-loops.
//
// R4 post-mortem: (1024,4) -> VGPR 64 -> scratch spill (FETCH +15MB, WRITE
// +30MB). Reverted to 512thr/(512,2) v9 base (68us, VGPR 124, no spill).
//
// R5 theory: v9's stall is waitcnt COARSENESS, not issue distance — compiler
// holds ~1 iter lookahead but emits a conservative wait covering the
// just-issued next-iteration loads before each MFMA cluster, exposing full
// L2 latency every kc for both waves on the SIMD. Fix (rule #18 pattern):
// B-frag loads via asm volatile global_load_dwordx4 (invisible to the
// compiler's waitcnt tracker), depth-3 rings, hand-placed
// s_waitcnt vmcnt(8/12) so TWO iterations of loads stay in flight across
// the MFMA clusters, sched_barrier(0) fencing MFMA hoisting.
// Counted-wait safety: K-loops contain no compiler-tracked VMEM, and
// untracked loads older than tracked ones only cause over-waiting.
//
// LDS map unchanged (160KB): A [64][768] f16 swizzled [0,98304) alive
// through epilogue (gate from LDS); P [64][512] f16 swizzled [98304,163840);
// red_max/red_sum alias P head (X3 WAR). Barrier-free K-loops; B-frags
// direct from L2-resident Qh/QhT.
// ---------------------------------------------------------------------------
#define CM        64
#define A_SLOTS   96          // 16B slots per A row (768 f16)
#define P_OFF     98304
#define P_SLOTS   64          // 16B slots per P row (512 f16)
#define SMEM_BYTES 163840

__device__ __forceinline__ f16x8 gload16(const _Float16* p) {
    f16x8 v;
    asm volatile("global_load_dwordx4 %0, %1, off" : "=&v"(v) : "v"(p));
    return v;
}
#define VMCNT(n) asm volatile("s_waitcnt vmcnt(" #n ")")

__global__ __launch_bounds__(512, 2) void gated_attn(const float* __restrict__ ctx,
                                                     const _Float16* __restrict__ Qh,
                                                     const _Float16* __restrict__ QhT,
                                                     float* __restrict__ out) {
    __shared__ __align__(16) char smem[SMEM_BYTES];
    float (*red_max)[64] = (float (*)[64])(smem + P_OFF);
    float (*red_sum)[64] = (float (*)[64])(smem + P_OFF + 2048);

    const int b    = blockIdx.x & 7;          // XCD-affine batch
    const int c0   = (blockIdx.x >> 3) * CM;
    const int t    = threadIdx.x;
    const int w    = t >> 6;                  // wave 0..7
    const int lane = t & 63;
    const int quad = lane >> 4;
    const int l15  = lane & 15;

    const float*    Cb  = ctx + ((size_t)b * LC + c0) * DD;
    const _Float16* Qhb = Qh  + (size_t)b * LQ * DD;
    const _Float16* QTb = QhT + (size_t)b * DD * LQ;

    const _Float16* bqb = Qhb + (size_t)(w * 64 + l15) * DD + quad * 8;
    const _Float16* cqb = QTb + (size_t)(w * 96 + l15) * LQ + quad * 8;

    // -------- Phase-A B-frag preload (ring slots 0,1) --------
    f16x8 bP[3][4];
#pragma unroll
    for (int s = 0; s < 2; s++)
#pragma unroll
        for (int nt = 0; nt < 4; nt++)
            bP[s][nt] = gload16(bqb + (size_t)(nt * 16) * DD + s * 32);

    // ---------------- Stage A-tile (ctx f32 -> f16, swizzled) ----------------
#pragma unroll
    for (int i = 0; i < 12; i++) {
        const int idx = i * 512 + t;
        const int row = idx / 96;
        const int c16 = idx % 96;
        const float* p = Cb + (size_t)row * DD + c16 * 8;
        f32x4 f0 = *(const f32x4*)p;
        f32x4 f1 = *(const f32x4*)(p + 4);
        f16x8 v;
        v[0] = (_Float16)f0.x; v[1] = (_Float16)f0.y;
        v[2] = (_Float16)f0.z; v[3] = (_Float16)f0.w;
        v[4] = (_Float16)f1.x; v[5] = (_Float16)f1.y;
        v[6] = (_Float16)f1.z; v[7] = (_Float16)f1.w;
        const int s16 = row * A_SLOTS + ((c16 & ~7) | ((c16 ^ row) & 7));
        *(f16x8*)(smem + (size_t)s16 * 16) = v;
    }
    __syncthreads();   // publish ldsA

    // ---------------- Phase A: S = A @ Qh^T (no barriers, counted vmcnt) -----
    f32x4 acc[4][4];
#pragma unroll
    for (int mt = 0; mt < 4; mt++)
#pragma unroll
        for (int nt = 0; nt < 4; nt++)
            acc[mt][nt] = (f32x4){0.f, 0.f, 0.f, 0.f};

    f16x8 aP[2][4];
    {
        const int sw0 = (quad & ~7) | ((quad ^ l15) & 7);   // kc=0, c16=quad
#pragma unroll
        for (int mt = 0; mt < 4; mt++)
            aP[0][mt] = *(const f16x8*)(smem + (size_t)((mt * 16 + l15) * A_SLOTS + sw0) * 16);
    }

#pragma unroll
    for (int kc = 0; kc < 24; kc++) {
        if (kc + 2 < 24) {
#pragma unroll
            for (int nt = 0; nt < 4; nt++)
                bP[(kc + 2) % 3][nt] = gload16(bqb + (size_t)(nt * 16) * DD + (kc + 2) * 32);
        }
        if (kc + 1 < 24) {
            const int c16 = (kc + 1) * 4 + quad;
            const int sw  = (c16 & ~7) | ((c16 ^ l15) & 7);
#pragma unroll
            for (int mt = 0; mt < 4; mt++)
                aP[(kc + 1) & 1][mt] = *(const f16x8*)(smem + (size_t)((mt * 16 + l15) * A_SLOTS + sw) * 16);
        }
        // slot kc must be complete; slots kc+1, kc+2 (8 loads) stay in flight
        if (kc < 22)       VMCNT(8);
        else if (kc == 22) VMCNT(4);
        else               VMCNT(0);
        __builtin_amdgcn_sched_barrier(0);
        __builtin_amdgcn_s_setprio(1);
#pragma unroll
        for (int nt = 0; nt < 4; nt++)
#pragma unroll
            for (int mt = 0; mt < 4; mt++)
                acc[mt][nt] = __builtin_amdgcn_mfma_f32_16x16x32_f16(aP[kc & 1][mt], bP[kc % 3][nt], acc[mt][nt], 0, 0, 0);
        __builtin_amdgcn_s_setprio(0);
    }

    // -------- Phase-C B-frag preload (ring slots 0,1): overlap softmax ------
    f16x8 cP[3][6];
#pragma unroll
    for (int s = 0; s < 2; s++)
#pragma unroll
        for (int nt = 0; nt < 6; nt++)
            cP[s][nt] = gload16(cqb + (size_t)(nt * 16) * LQ + s * 32);

    // ---------------- Softmax over q ----------------
    float rm[4][4];
#pragma unroll
    for (int mt = 0; mt < 4; mt++)
#pragma unroll
        for (int r = 0; r < 4; r++)
            rm[mt][r] = -1e30f;
#pragma unroll
    for (int mt = 0; mt < 4; mt++)
#pragma unroll
        for (int nt = 0; nt < 4; nt++) {
            rm[mt][0] = fmaxf(rm[mt][0], acc[mt][nt].x);
            rm[mt][1] = fmaxf(rm[mt][1], acc[mt][nt].y);
            rm[mt][2] = fmaxf(rm[mt][2], acc[mt][nt].z);
            rm[mt][3] = fmaxf(rm[mt][3], acc[mt][nt].w);
        }
#pragma unroll
    for (int off = 1; off < 16; off <<= 1)
#pragma unroll
        for (int mt = 0; mt < 4; mt++)
#pragma unroll
            for (int r = 0; r < 4; r++)
                rm[mt][r] = fmaxf(rm[mt][r], __shfl_xor(rm[mt][r], off));
    if (l15 == 0) {
#pragma unroll
        for (int mt = 0; mt < 4; mt++)
#pragma unroll
            for (int r = 0; r < 4; r++)
                red_max[w][mt * 16 + quad * 4 + r] = rm[mt][r];
    }
    __syncthreads();   // [X1] publish red_max (all phase-A LDS reads drained)

    float fm[4][4];
#pragma unroll
    for (int mt = 0; mt < 4; mt++)
#pragma unroll
        for (int r = 0; r < 4; r++) {
            const int row = mt * 16 + quad * 4 + r;
            float m0 = fmaxf(fmaxf(red_max[0][row], red_max[1][row]),
                             fmaxf(red_max[2][row], red_max[3][row]));
            float m1 = fmaxf(fmaxf(red_max[4][row], red_max[5][row]),
                             fmaxf(red_max[6][row], red_max[7][row]));
            fm[mt][r] = fmaxf(m0, m1);
        }
    float rs[4][4];
#pragma unroll
    for (int mt = 0; mt < 4; mt++)
#pragma unroll
        for (int r = 0; r < 4; r++)
            rs[mt][r] = 0.f;
#pragma unroll
    for (int mt = 0; mt < 4; mt++)
#pragma unroll
        for (int nt = 0; nt < 4; nt++) {
            float e0 = __expf(acc[mt][nt].x - fm[mt][0]);
            float e1 = __expf(acc[mt][nt].y - fm[mt][1]);
            float e2 = __expf(acc[mt][nt].z - fm[mt][2]);
            float e3 = __expf(acc[mt][nt].w - fm[mt][3]);
            acc[mt][nt].x = e0; acc[mt][nt].y = e1;
            acc[mt][nt].z = e2; acc[mt][nt].w = e3;
            rs[mt][0] += e0; rs[mt][1] += e1; rs[mt][2] += e2; rs[mt][3] += e3;
        }
#pragma unroll
    for (int off = 1; off < 16; off <<= 1)
#pragma unroll
        for (int mt = 0; mt < 4; mt++)
#pragma unroll
            for (int r = 0; r < 4; r++)
                rs[mt][r] += __shfl_xor(rs[mt][r], off);
    if (l15 == 0) {
#pragma unroll
        for (int mt = 0; mt < 4; mt++)
#pragma unroll
            for (int r = 0; r < 4; r++)
                red_sum[w][mt * 16 + quad * 4 + r] = rs[mt][r];
    }
    __syncthreads();   // [X2] publish red_sum

#pragma unroll
    for (int mt = 0; mt < 4; mt++)
#pragma unroll
        for (int r = 0; r < 4; r++) {
            const int row = mt * 16 + quad * 4 + r;
            float s = 0.f;
#pragma unroll
            for (int j = 0; j < 8; j++) s += red_sum[j][row];
            const float inv = 1.0f / s;
#pragma unroll
            for (int nt = 0; nt < 4; nt++) {
                acc[mt][nt].x = (r == 0) ? acc[mt][nt].x * inv : acc[mt][nt].x;
                acc[mt][nt].y = (r == 1) ? acc[mt][nt].y * inv : acc[mt][nt].y;
                acc[mt][nt].z = (r == 2) ? acc[mt][nt].z * inv : acc[mt][nt].z;
                acc[mt][nt].w = (r == 3) ? acc[mt][nt].w * inv : acc[mt][nt].w;
            }
        }
    __syncthreads();   // [X3] red region reads drained; P writes may overwrite it

    // write P (f16, swizzled)
#pragma unroll
    for (int mt = 0; mt < 4; mt++)
#pragma unroll
        for (int r = 0; r < 4; r++) {
            const int row = mt * 16 + quad * 4 + r;
#pragma unroll
            for (int nt = 0; nt < 4; nt++) {
                const int q = w * 64 + nt * 16 + l15;
                float v = (r == 0 ? acc[mt][nt].x : r == 1 ? acc[mt][nt].y
                          : r == 2 ? acc[mt][nt].z : acc[mt][nt].w);
                const int c16 = q >> 3;
                const int s16 = row * P_SLOTS + ((c16 & ~7) | ((c16 ^ row) & 7));
                *(_Float16*)(smem + P_OFF + (size_t)s16 * 16 + (q & 7) * 2) = (_Float16)v;
            }
        }
    __syncthreads();   // [X4] publish P

    // ---------------- Phase C: awq = P @ Q (no barriers, counted vmcnt) -----
    f32x4 acc2[4][6];
#pragma unroll
    for (int mt = 0; mt < 4; mt++)
#pragma unroll
        for (int nt = 0; nt < 6; nt++)
            acc2[mt][nt] = (f32x4){0.f, 0.f, 0.f, 0.f};

    f16x8 pP[2][4];
    {
        const int sw0 = (quad & ~7) | ((quad ^ l15) & 7);   // kc=0, c16=quad
#pragma unroll
        for (int mt = 0; mt < 4; mt++)
            pP[0][mt] = *(const f16x8*)(smem + P_OFF + (size_t)((mt * 16 + l15) * P_SLOTS + sw0) * 16);
    }

#pragma unroll
    for (int kc = 0; kc < 16; kc++) {
        if (kc + 2 < 16) {
#pragma unroll
            for (int nt = 0; nt < 6; nt++)
                cP[(kc + 2) % 3][nt] = gload16(cqb + (size_t)(nt * 16) * LQ + (kc + 2) * 32);
        }
        if (kc + 1 < 16) {
            const int c16 = (kc + 1) * 4 + quad;
            const int sw  = (c16 & ~7) | ((c16 ^ l15) & 7);
#pragma unroll
            for (int mt = 0; mt < 4; mt++)
                pP[(kc + 1) & 1][mt] = *(const f16x8*)(smem + P_OFF + (size_t)((mt * 16 + l15) * P_SLOTS + sw) * 16);
        }
        // slot kc must be complete; slots kc+1, kc+2 (12 loads) stay in flight
        if (kc < 14)       VMCNT(12);
        else if (kc == 14) VMCNT(6);
        else               VMCNT(0);
        __builtin_amdgcn_sched_barrier(0);
        __builtin_amdgcn_s_setprio(1);
#pragma unroll
        for (int nt = 0; nt < 6; nt++)
#pragma unroll
            for (int mt = 0; mt < 4; mt++)
                acc2[mt][nt] = __builtin_amdgcn_mfma_f32_16x16x32_f16(pP[kc & 1][mt], cP[kc % 3][nt], acc2[mt][nt], 0, 0, 0);
        __builtin_amdgcn_s_setprio(0);
    }

    // ---------------- Epilogue: out = gate(LDS A-tile) * awq ----------------
#pragma unroll
    for (int mt = 0; mt < 4; mt++)
#pragma unroll
        for (int nt = 0; nt < 6; nt++) {
            const int col = w * 96 + nt * 16 + l15;
            const int c16 = col >> 3;
            const int sub = col & 7;
#pragma unroll
            for (int r = 0; r < 4; r++) {
                const int rl  = mt * 16 + quad * 4 + r;
                const int s16 = rl * A_SLOTS + ((c16 & ~7) | ((c16 ^ rl) & 7));
                const float g = (float)*(const _Float16*)(smem + (size_t)s16 * 16 + sub * 2);
                float v = (r == 0 ? acc2[mt][nt].x : r == 1 ? acc2[mt][nt].y
                          : r == 2 ? acc2[mt][nt].z : acc2[mt][nt].w);
                out[((size_t)b * LC + c0 + rl) * DD + col] = g * v;
            }
        }
}

extern "C" void kernel_launch(void* const* d_in, const int* in_sizes, int n_in,
                              void* d_out, int out_size, void* d_ws, size_t ws_size,
                              hipStream_t stream) {
    const float* ctx = (const float*)d_in[0];   // [8][2048][768] f32
    const float* q   = (const float*)d_in[1];   // [8][512][768]  f32
    float* out = (float*)d_out;

    const size_t nQ = (size_t)NB * LQ * DD;     // 3,145,728
    _Float16* Qh  = (_Float16*)d_ws;
    _Float16* QhT = Qh + nQ;

    preconvert_q<<<dim3(NB * 96), dim3(256), 0, stream>>>(q, Qh, QhT);
    gated_attn<<<dim3(NB * (LC / CM)), dim3(512), 0, stream>>>(ctx, Qh, QhT, out);
}

// Round 7
// 151.760 us; speedup vs baseline: 1.1023x; 1.0036x over previous
//
#include <hip/hip_runtime.h>

// Problem constants (from reference setup_inputs)
#define NB 8
#define LQ 512
#define LC 2048
#define DD 768

typedef _Float16 f16x8 __attribute__((ext_vector_type(8)));
typedef _Float16 f16x4 __attribute__((ext_vector_type(4)));
typedef float    f32x4 __attribute__((ext_vector_type(4)));

// ---------------------------------------------------------------------------
// K0: convert Q fp32 -> Qh [b][q][d] fp16  AND  QhT [b][d][q] fp16
// ---------------------------------------------------------------------------
__global__ __launch_bounds__(256) void preconvert_q(const float* __restrict__ Q,
                                                    _Float16* __restrict__ Qh,
                                                    _Float16* __restrict__ QhT) {
    __shared__ _Float16 lt[64][68];
    const int blk = blockIdx.x;
    const int b   = blk / 96;
    const int rem = blk % 96;
    const int q0  = (rem / 12) * 64;
    const int d0  = (rem % 12) * 64;
    const int t   = threadIdx.x;
    const int tr  = t >> 4;
    const int tc  = t & 15;

    const float* Qb  = Q  + ((size_t)b * LQ + q0) * DD + d0;
    _Float16*    Qhb = Qh + ((size_t)b * LQ + q0) * DD + d0;

#pragma unroll
    for (int i = 0; i < 4; i++) {
        const int row = i * 16 + tr;
        const int col = tc * 4;
        f32x4 v = *(const f32x4*)(Qb + (size_t)row * DD + col);
        f16x4 h;
        h.x = (_Float16)v.x; h.y = (_Float16)v.y;
        h.z = (_Float16)v.z; h.w = (_Float16)v.w;
        *(f16x4*)(Qhb + (size_t)row * DD + col) = h;
        *(f16x4*)&lt[row][col] = h;
    }
    __syncthreads();

    _Float16* QTb = QhT + ((size_t)b * DD + d0) * LQ + q0;
#pragma unroll
    for (int i = 0; i < 4; i++) {
        const int drow = i * 16 + tr;
        const int qc   = tc * 4;
        f16x4 h;
        h.x = lt[qc + 0][drow];
        h.y = lt[qc + 1][drow];
        h.z = lt[qc + 2][drow];
        h.w = lt[qc + 3][drow];
        *(f16x4*)(QTb + (size_t)drow * LQ + qc) = h;
    }
}

// ---------------------------------------------------------------------------
// Main fused kernel v12b: global_load_lds B-staging, double-buffered, one
// __syncthreads per 32-wide chunk. Resubmission of v12 (R6 bench was an
// infra failure, no data) with two changes:
//  - plain __syncthreads() chunk barriers (equivalent here: only the OWN
//    chunk's DMA is outstanding at the barrier; next chunk's DMA is issued
//    after it) — removes raw-asm barrier risk.
//  - full 2-way staging swizzle: sse/read-slot include ((row>>2)&3) so a
//    16-lane read group covers all 8 bank-group bases (old version was
//    4-way on rows 4 apart).
//
// Theory (R5 post-mortem): direct per-lane B-frag loads scatter 64 lanes
// over 16 rows (1536B stride) = 16 line requests/instr -> per-CU L1/TA
// request path saturates at ~0.7 TB/s/XCD. Line-contiguous DMA staging
// (R0) sustained 1.14 TB/s/XCD even with naive barriers. This kernel has
// CM=64 traffic (8x less than R0) + DMA staging + non-draining schedule:
//   iter kc: barrier (drains chunk kc, issued one full MFMA-block ago)
//            -> issue DMA chunk kc+1 -> ds_read frags -> MFMA.
//
// LDS (160KB exact, phase-aliased):
//   phase A: A-tile [64][768] f16 swz [0,98304) | Bdbuf 2x32KB [98304,163840)
//   softmax: red_max/red_sum [8][64] f32 at [65536,69632) (A-tile dead)
//   phase C: P [64][512] f16 swz [0,65536) | Cdbuf 2x48KB [65536,163840)
// Epilogue gate re-reads ctx from global (L3-resident).
//
// Staging layout: chunk row r lives at buffer byte r*64; 16B slot s of row r
// holds column s ^ (r&3) ^ ((r>>2)&3)  (pre-swizzled GLOBAL source per lane;
// LDS dest stays linear = DMA-compatible). Reader of column `quad` at row rr
// uses slot quad ^ (rr&3) ^ ((rr>>2)&3) — lane-constant, 2-way residual.
// ---------------------------------------------------------------------------
#define CM        64
#define A_SLOTS   96          // 16B slots per A row (768 f16)
#define P_SLOTS   64          // 16B slots per P row (512 f16)
#define RED_OFF   65536
#define BBUF_OFF  98304       // two 32KB buffers
#define CBUF_OFF  65536       // two 48KB buffers
#define SMEM_BYTES 163840

__device__ __forceinline__ void dma16(const _Float16* g, char* l) {
    __builtin_amdgcn_global_load_lds(
        (const __attribute__((address_space(1))) unsigned int*)g,
        (__attribute__((address_space(3))) unsigned int*)l,
        16, 0, 0);
}

__global__ __launch_bounds__(512, 2) void gated_attn(const float* __restrict__ ctx,
                                                     const _Float16* __restrict__ Qh,
                                                     const _Float16* __restrict__ QhT,
                                                     float* __restrict__ out) {
    __shared__ __align__(16) char smem[SMEM_BYTES];
    float (*red_max)[64] = (float (*)[64])(smem + RED_OFF);
    float (*red_sum)[64] = (float (*)[64])(smem + RED_OFF + 2048);

    const int b    = blockIdx.x & 7;          // XCD-affine batch
    const int c0   = (blockIdx.x >> 3) * CM;
    const int t    = threadIdx.x;
    const int w    = t >> 6;                  // wave 0..7
    const int lane = t & 63;
    const int quad = lane >> 4;
    const int l15  = lane & 15;

    const float*    Cb  = ctx + ((size_t)b * LC + c0) * DD;
    const _Float16* Qhb = Qh  + (size_t)b * LQ * DD;
    const _Float16* QTb = QhT + (size_t)b * DD * LQ;

    // staging thread roles: srow = chunk row (t>>2), sse = pre-swizzled 16B col
    const int srow = t >> 2;                               // 0..127
    const int sse  = (t & 3) ^ (srow & 3) ^ ((srow >> 2) & 3);
    const _Float16* stA = Qhb + (size_t)srow * DD + sse * 8;
    const _Float16* stC = QTb + (size_t)srow * LQ + sse * 8;
    char* ldsW = smem + (size_t)w * 1024;                  // wave-uniform DMA base

    // fragment-read slot (lane-constant): column quad at row rr where
    // rr&3 == l15&3 and (rr>>2)&3 == (l15>>2)&3 for all nt/w strides (mult of 16)
    const int bsub = ((quad ^ (l15 & 3) ^ ((l15 >> 2) & 3)) & 3) * 16;

    // -------- DMA chunk 0 of phase A (drained by the staging barrier) ------
#pragma unroll
    for (int j = 0; j < 4; j++)
        dma16(stA + (size_t)(j * 128) * DD, ldsW + BBUF_OFF + j * 8192);

    // ---------------- Stage A-tile (ctx f32 -> f16, swizzled) ----------------
#pragma unroll
    for (int i = 0; i < 12; i++) {
        const int idx = i * 512 + t;
        const int row = idx / 96;
        const int c16 = idx % 96;
        const float* p = Cb + (size_t)row * DD + c16 * 8;
        f32x4 f0 = *(const f32x4*)p;
        f32x4 f1 = *(const f32x4*)(p + 4);
        f16x8 v;
        v[0] = (_Float16)f0.x; v[1] = (_Float16)f0.y;
        v[2] = (_Float16)f0.z; v[3] = (_Float16)f0.w;
        v[4] = (_Float16)f1.x; v[5] = (_Float16)f1.y;
        v[6] = (_Float16)f1.z; v[7] = (_Float16)f1.w;
        const int s16 = row * A_SLOTS + ((c16 & ~7) | ((c16 ^ row) & 7));
        *(f16x8*)(smem + (size_t)s16 * 16) = v;
    }
    __syncthreads();   // publish ldsA; drains chunk-0 DMA

    // ---------------- Phase A: S = A @ Qh^T ----------------
    f32x4 acc[4][4];
#pragma unroll
    for (int mt = 0; mt < 4; mt++)
#pragma unroll
        for (int nt = 0; nt < 4; nt++)
            acc[mt][nt] = (f32x4){0.f, 0.f, 0.f, 0.f};

#pragma unroll
    for (int kc = 0; kc < 24; kc++) {
        if (kc > 0) __syncthreads();          // chunk kc landed everywhere
        if (kc + 1 < 24) {                    // issue next chunk's DMA first
            char* nb = ldsW + BBUF_OFF + ((kc + 1) & 1) * 32768;
            const _Float16* src = stA + (kc + 1) * 32;
#pragma unroll
            for (int j = 0; j < 4; j++)
                dma16(src + (size_t)(j * 128) * DD, nb + j * 8192);
        }
        const char* bbuf = smem + BBUF_OFF + (kc & 1) * 32768;
        const int c16 = kc * 4 + quad;
        const int sw  = (c16 & ~7) | ((c16 ^ l15) & 7);
        f16x8 a[4], bq[4];
#pragma unroll
        for (int mt = 0; mt < 4; mt++)
            a[mt] = *(const f16x8*)(smem + (size_t)((mt * 16 + l15) * A_SLOTS + sw) * 16);
#pragma unroll
        for (int nt = 0; nt < 4; nt++)
            bq[nt] = *(const f16x8*)(bbuf + (size_t)(w * 64 + nt * 16 + l15) * 64 + bsub);
        __builtin_amdgcn_s_setprio(1);
#pragma unroll
        for (int nt = 0; nt < 4; nt++)
#pragma unroll
            for (int mt = 0; mt < 4; mt++)
                acc[mt][nt] = __builtin_amdgcn_mfma_f32_16x16x32_f16(a[mt], bq[nt], acc[mt][nt], 0, 0, 0);
        __builtin_amdgcn_s_setprio(0);
    }

    // ---------------- Softmax over q ----------------
    float rm[4][4];
#pragma unroll
    for (int mt = 0; mt < 4; mt++)
#pragma unroll
        for (int r = 0; r < 4; r++)
            rm[mt][r] = -1e30f;
#pragma unroll
    for (int mt = 0; mt < 4; mt++)
#pragma unroll
        for (int nt = 0; nt < 4; nt++) {
            rm[mt][0] = fmaxf(rm[mt][0], acc[mt][nt].x);
            rm[mt][1] = fmaxf(rm[mt][1], acc[mt][nt].y);
            rm[mt][2] = fmaxf(rm[mt][2], acc[mt][nt].z);
            rm[mt][3] = fmaxf(rm[mt][3], acc[mt][nt].w);
        }
#pragma unroll
    for (int off = 1; off < 16; off <<= 1)
#pragma unroll
        for (int mt = 0; mt < 4; mt++)
#pragma unroll
            for (int r = 0; r < 4; r++)
                rm[mt][r] = fmaxf(rm[mt][r], __shfl_xor(rm[mt][r], off));
    if (l15 == 0) {
#pragma unroll
        for (int mt = 0; mt < 4; mt++)
#pragma unroll
            for (int r = 0; r < 4; r++)
                red_max[w][mt * 16 + quad * 4 + r] = rm[mt][r];
    }
    __syncthreads();   // [X1] publish red_max (phase-A LDS reads drained)

    float fm[4][4];
#pragma unroll
    for (int mt = 0; mt < 4; mt++)
#pragma unroll
        for (int r = 0; r < 4; r++) {
            const int row = mt * 16 + quad * 4 + r;
            float m0 = fmaxf(fmaxf(red_max[0][row], red_max[1][row]),
                             fmaxf(red_max[2][row], red_max[3][row]));
            float m1 = fmaxf(fmaxf(red_max[4][row], red_max[5][row]),
                             fmaxf(red_max[6][row], red_max[7][row]));
            fm[mt][r] = fmaxf(m0, m1);
        }
    float rs[4][4];
#pragma unroll
    for (int mt = 0; mt < 4; mt++)
#pragma unroll
        for (int r = 0; r < 4; r++)
            rs[mt][r] = 0.f;
#pragma unroll
    for (int mt = 0; mt < 4; mt++)
#pragma unroll
        for (int nt = 0; nt < 4; nt++) {
            float e0 = __expf(acc[mt][nt].x - fm[mt][0]);
            float e1 = __expf(acc[mt][nt].y - fm[mt][1]);
            float e2 = __expf(acc[mt][nt].z - fm[mt][2]);
            float e3 = __expf(acc[mt][nt].w - fm[mt][3]);
            acc[mt][nt].x = e0; acc[mt][nt].y = e1;
            acc[mt][nt].z = e2; acc[mt][nt].w = e3;
            rs[mt][0] += e0; rs[mt][1] += e1; rs[mt][2] += e2; rs[mt][3] += e3;
        }
#pragma unroll
    for (int off = 1; off < 16; off <<= 1)
#pragma unroll
        for (int mt = 0; mt < 4; mt++)
#pragma unroll
            for (int r = 0; r < 4; r++)
                rs[mt][r] += __shfl_xor(rs[mt][r], off);
    if (l15 == 0) {
#pragma unroll
        for (int mt = 0; mt < 4; mt++)
#pragma unroll
            for (int r = 0; r < 4; r++)
                red_sum[w][mt * 16 + quad * 4 + r] = rs[mt][r];
    }
    __syncthreads();   // [X2] publish red_sum

#pragma unroll
    for (int mt = 0; mt < 4; mt++)
#pragma unroll
        for (int r = 0; r < 4; r++) {
            const int row = mt * 16 + quad * 4 + r;
            float s = 0.f;
#pragma unroll
            for (int j = 0; j < 8; j++) s += red_sum[j][row];
            const float inv = 1.0f / s;
#pragma unroll
            for (int nt = 0; nt < 4; nt++) {
                acc[mt][nt].x = (r == 0) ? acc[mt][nt].x * inv : acc[mt][nt].x;
                acc[mt][nt].y = (r == 1) ? acc[mt][nt].y * inv : acc[mt][nt].y;
                acc[mt][nt].z = (r == 2) ? acc[mt][nt].z * inv : acc[mt][nt].z;
                acc[mt][nt].w = (r == 3) ? acc[mt][nt].w * inv : acc[mt][nt].w;
            }
        }
    __syncthreads();   // [X3] red reads drained; Cbuf0 DMA may overwrite it

    // -------- DMA chunk 0 of phase C (overlaps P-write; drained at X4) ------
#pragma unroll
    for (int j = 0; j < 6; j++)
        dma16(stC + (size_t)(j * 128) * LQ, ldsW + CBUF_OFF + j * 8192);

    // write P (f16, swizzled) at [0,64K)
#pragma unroll
    for (int mt = 0; mt < 4; mt++)
#pragma unroll
        for (int r = 0; r < 4; r++) {
            const int row = mt * 16 + quad * 4 + r;
#pragma unroll
            for (int nt = 0; nt < 4; nt++) {
                const int q = w * 64 + nt * 16 + l15;
                float v = (r == 0 ? acc[mt][nt].x : r == 1 ? acc[mt][nt].y
                          : r == 2 ? acc[mt][nt].z : acc[mt][nt].w);
                const int c16 = q >> 3;
                const int s16 = row * P_SLOTS + ((c16 & ~7) | ((c16 ^ row) & 7));
                *(_Float16*)(smem + (size_t)s16 * 16 + (q & 7) * 2) = (_Float16)v;
            }
        }
    __syncthreads();   // [X4] publish P; drains chunk-0 DMA

    // ---------------- Phase C: awq = P @ Q ----------------
    f32x4 acc2[4][6];
#pragma unroll
    for (int mt = 0; mt < 4; mt++)
#pragma unroll
        for (int nt = 0; nt < 6; nt++)
            acc2[mt][nt] = (f32x4){0.f, 0.f, 0.f, 0.f};

#pragma unroll
    for (int kc = 0; kc < 16; kc++) {
        if (kc > 0) __syncthreads();          // chunk kc landed everywhere
        if (kc + 1 < 16) {                    // issue next chunk's DMA first
            char* nb = ldsW + CBUF_OFF + ((kc + 1) & 1) * 49152;
            const _Float16* src = stC + (kc + 1) * 32;
#pragma unroll
            for (int j = 0; j < 6; j++)
                dma16(src + (size_t)(j * 128) * LQ, nb + j * 8192);
        }
        const char* cbuf = smem + CBUF_OFF + (kc & 1) * 49152;
        const int c16 = kc * 4 + quad;
        const int sw  = (c16 & ~7) | ((c16 ^ l15) & 7);
        f16x8 pf[4], cq[6];
#pragma unroll
        for (int mt = 0; mt < 4; mt++)
            pf[mt] = *(const f16x8*)(smem + (size_t)((mt * 16 + l15) * P_SLOTS + sw) * 16);
#pragma unroll
        for (int nt = 0; nt < 6; nt++)
            cq[nt] = *(const f16x8*)(cbuf + (size_t)(w * 96 + nt * 16 + l15) * 64 + bsub);
        __builtin_amdgcn_s_setprio(1);
#pragma unroll
        for (int nt = 0; nt < 6; nt++)
#pragma unroll
            for (int mt = 0; mt < 4; mt++)
                acc2[mt][nt] = __builtin_amdgcn_mfma_f32_16x16x32_f16(pf[mt], cq[nt], acc2[mt][nt], 0, 0, 0);
        __builtin_amdgcn_s_setprio(0);
    }

    // ---------------- Epilogue: out = ctx * awq (ctx L3-resident) ----------
#pragma unroll
    for (int mt = 0; mt < 4; mt++)
#pragma unroll
        for (int nt = 0; nt < 6; nt++) {
            const int col = w * 96 + nt * 16 + l15;
#pragma unroll
            for (int r = 0; r < 4; r++) {
                const int rl  = mt * 16 + quad * 4 + r;
                const size_t idx = ((size_t)b * LC + c0 + rl) * DD + col;
                float v = (r == 0 ? acc2[mt][nt].x : r == 1 ? acc2[mt][nt].y
                          : r == 2 ? acc2[mt][nt].z : acc2[mt][nt].w);
                out[idx] = ctx[idx] * v;
            }
        }
}

extern "C" void kernel_launch(void* const* d_in, const int* in_sizes, int n_in,
                              void* d_out, int out_size, void* d_ws, size_t ws_size,
                              hipStream_t stream) {
    const float* ctx = (const float*)d_in[0];   // [8][2048][768] f32
    const float* q   = (const float*)d_in[1];   // [8][512][768]  f32
    float* out = (float*)d_out;

    const size_t nQ = (size_t)NB * LQ * DD;     // 3,145,728
    _Float16* Qh  = (_Float16*)d_ws;
    _Float16* QhT = Qh + nQ;

    preconvert_q<<<dim3(NB * 96), dim3(256), 0, stream>>>(q, Qh, QhT);
    gated_attn<<<dim3(NB * (LC / CM)), dim3(512), 0, stream>>>(ctx, Qh, QhT, out);
}